// Round 5
// baseline (206.642 us; speedup 1.0000x reference)
//
#include <hip/hip_runtime.h>

#define SS 1024
#define GG 10
#define FF 5
#define BB 8
#define CC 3
#define KK (2 * FF + 1)

// ---------------------------------------------------------------------------
// Kernel 1: smooth the (B,1,G,G) offset grids with an 11x11 gaussian
// (edge-padded), scale by max_offset, clip, store field [B][2][G][G] in ws.
// ---------------------------------------------------------------------------
__global__ __launch_bounds__(256) void rds_smooth_kernel(
    const float* __restrict__ ox, const float* __restrict__ oy,
    const float* __restrict__ w, const void* __restrict__ max_move_p,
    float* __restrict__ gs)
{
    int idx = blockIdx.x * 256 + threadIdx.x;
    if (idx >= BB * 2 * GG * GG) return;
    int j  = idx % GG;
    int i  = (idx / GG) % GG;
    int ch = (idx / (GG * GG)) % 2;
    int b  = idx / (2 * GG * GG);

    const float* o = (ch == 0 ? ox : oy) + b * GG * GG;

    // max_move: python scalar; hedge int32 vs float32 storage
    int mi = *(const int*)max_move_p;
    float mv = (mi >= -100000 && mi <= 100000) ? (float)mi : __int_as_float(mi);
    float max_offset = 2.0f * mv / (float)SS;

    float acc = 0.0f;
    for (int u = 0; u < KK; ++u) {
        int yy = min(max(i + u - FF, 0), GG - 1);
        for (int v = 0; v < KK; ++v) {
            int xx = min(max(j + v - FF, 0), GG - 1);
            acc += o[yy * GG + xx] * w[u * KK + v];
        }
    }
    acc *= max_offset;
    acc = fminf(fmaxf(acc, -max_offset), max_offset);
    gs[idx] = acc;
}

// ---------------------------------------------------------------------------
// Kernel 2: block = 4-row x 256-col tile. Thread t handles the same column in
// 4 vertically adjacent rows (p=0..3). All loads/stores lane-stride-4B
// coalesced; vertical stacking gives intra-thread cache-line reuse between
// px p's y1 row and px p+1's y0 row. x-direction upsample math hoisted out of
// the p loop; per-row y-interpolated fields in a rowf[4][2][10] LDS table.
// ---------------------------------------------------------------------------
__global__ __launch_bounds__(256, 4) void rds_deform_kernel(
    const float* __restrict__ x, const float* __restrict__ gs,
    float* __restrict__ out)
{
    int bx    = blockIdx.x;          // grid = BB * (SS/4) * 4
    int xseg  = bx & 3;
    int ytile = (bx >> 2) & 255;     // SS/4 = 256 tiles
    int b     = bx >> 10;
    int tid   = threadIdx.x;
    int ybase = ytile << 2;
    int xc    = (xseg << 8) + tid;

    __shared__ float rowf[4][2][GG];

    const float GdS = (float)GG / (float)SS;

    // Fill 4 rows x 2 channels x 10 cols of y-interpolated field
    if (tid < 80) {
        int p  = tid / 20;
        int r  = tid - p * 20;
        int ch = r / GG;
        int j  = r - ch * GG;
        int y  = ybase + p;
        float sy  = fmaxf(((float)y + 0.5f) * GdS - 0.5f, 0.0f);
        int   i0y = min((int)sy, GG - 1);
        int   i1y = min(i0y + 1, GG - 1);
        float wyu = sy - (float)i0y;
        const float* gb = gs + (b * 2 + ch) * GG * GG;
        rowf[p][ch][j] = gb[i0y * GG + j] + wyu * (gb[i1y * GG + j] - gb[i0y * GG + j]);
    }
    __syncthreads();

    // ---- x-direction quantities: once per thread ----
    float sx  = fmaxf(((float)xc + 0.5f) * GdS - 0.5f, 0.0f);
    int   i0x = min((int)sx, GG - 1);
    int   i1x = min(i0x + 1, GG - 1);
    float wxu = sx - (float)i0x;
    float pxc = (float)xc * (2.0f / (float)(SS - 1)) - 1.0f;

    int   o00[4], o01[4], o10[4], o11[4];
    float w00[4], w01[4], w10[4], w11[4];

    #pragma unroll
    for (int p = 0; p < 4; ++p) {
        float r0a = rowf[p][0][i0x], r0b = rowf[p][0][i1x];
        float r1a = rowf[p][1][i0x], r1b = rowf[p][1][i1x];
        float gxv = r0a + wxu * (r0b - r0a);
        float gyv = r1a + wxu * (r1b - r1a);

        float py  = (float)(ybase + p) * (2.0f / (float)(SS - 1)) - 1.0f;
        float gr0 = fminf(fmaxf(gxv + pxc, -1.0f), 1.0f);
        float gr1 = fminf(fmaxf(gyv + py,  -1.0f), 1.0f);

        // ((gr+1)*S-1)/2 == gr*512 + 511.5
        float ix = gr0 * 512.0f + 511.5f;
        float iy = gr1 * 512.0f + 511.5f;

        int   x0 = (int)floorf(ix);
        int   x1 = x0 + 1;
        int   y0 = (int)floorf(iy);
        int   y1 = y0 + 1;
        float wx = ix - (float)x0;
        float wy = iy - (float)y0;

        float mx0 = ((unsigned)x0 < (unsigned)SS) ? 1.0f : 0.0f;
        float mx1 = ((unsigned)x1 < (unsigned)SS) ? 1.0f : 0.0f;
        float my0 = ((unsigned)y0 < (unsigned)SS) ? 1.0f : 0.0f;
        float my1 = ((unsigned)y1 < (unsigned)SS) ? 1.0f : 0.0f;

        w00[p] = (1.0f - wy) * (1.0f - wx) * my0 * mx0;
        w01[p] = (1.0f - wy) * wx          * my0 * mx1;
        w10[p] = wy          * (1.0f - wx) * my1 * mx0;
        w11[p] = wy          * wx          * my1 * mx1;

        int cx0 = min(max(x0, 0), SS - 1);
        int cx1 = min(max(x1, 0), SS - 1);
        int cy0 = min(max(y0, 0), SS - 1);
        int cy1 = min(max(y1, 0), SS - 1);

        o00[p] = cy0 * SS + cx0;
        o01[p] = cy0 * SS + cx1;
        o10[p] = cy1 * SS + cx0;
        o11[p] = cy1 * SS + cx1;
    }

    const float* xb = x + (size_t)b * CC * SS * SS;
    size_t obase = (((size_t)b * CC) * SS + ybase) * SS + xc;

    // p-inner load order: px p and p+1 touch overlapping input lines
    #pragma unroll
    for (int c = 0; c < CC; ++c) {
        const float* img = xb + (size_t)c * SS * SS;
        float v[4];
        #pragma unroll
        for (int p = 0; p < 4; ++p) {
            v[p] = img[o00[p]] * w00[p] + img[o01[p]] * w01[p]
                 + img[o10[p]] * w10[p] + img[o11[p]] * w11[p];
        }
        #pragma unroll
        for (int p = 0; p < 4; ++p) {
            out[obase + (size_t)c * SS * SS + (size_t)(p * SS)] = v[p];
        }
    }
}

extern "C" void kernel_launch(void* const* d_in, const int* in_sizes, int n_in,
                              void* d_out, int out_size, void* d_ws, size_t ws_size,
                              hipStream_t stream) {
    const float* x        = (const float*)d_in[0];
    const float* offset_x = (const float*)d_in[1];
    const float* offset_y = (const float*)d_in[2];
    const float* weight   = (const float*)d_in[3];
    const void*  max_move = d_in[4];
    float* out = (float*)d_out;
    float* gs  = (float*)d_ws;   // [B][2][G][G] smoothed, scaled, clipped field

    int n1 = BB * 2 * GG * GG;   // 1600
    rds_smooth_kernel<<<(n1 + 255) / 256, 256, 0, stream>>>(
        offset_x, offset_y, weight, max_move, gs);

    int nblocks = BB * (SS / 4) * 4;   // 8192: (b, ytile, xseg)
    rds_deform_kernel<<<nblocks, 256, 0, stream>>>(x, gs, out);
}

// Round 6
// 201.183 us; speedup vs baseline: 1.0271x; 1.0271x over previous
//
#include <hip/hip_runtime.h>

#define SS 1024
#define GG 10
#define FF 5
#define BB 8
#define CC 3
#define KK (2 * FF + 1)

typedef float f32x2 __attribute__((ext_vector_type(2), aligned(4)));

// ---------------------------------------------------------------------------
// Kernel 1: smooth the (B,1,G,G) offset grids with an 11x11 gaussian
// (edge-padded), scale by max_offset, clip, store field [B][2][G][G] in ws.
// ---------------------------------------------------------------------------
__global__ __launch_bounds__(256) void rds_smooth_kernel(
    const float* __restrict__ ox, const float* __restrict__ oy,
    const float* __restrict__ w, const void* __restrict__ max_move_p,
    float* __restrict__ gs)
{
    int idx = blockIdx.x * 256 + threadIdx.x;
    if (idx >= BB * 2 * GG * GG) return;
    int j  = idx % GG;
    int i  = (idx / GG) % GG;
    int ch = (idx / (GG * GG)) % 2;
    int b  = idx / (2 * GG * GG);

    const float* o = (ch == 0 ? ox : oy) + b * GG * GG;

    // max_move: python scalar; hedge int32 vs float32 storage
    int mi = *(const int*)max_move_p;
    float mv = (mi >= -100000 && mi <= 100000) ? (float)mi : __int_as_float(mi);
    float max_offset = 2.0f * mv / (float)SS;

    float acc = 0.0f;
    for (int u = 0; u < KK; ++u) {
        int yy = min(max(i + u - FF, 0), GG - 1);
        for (int v = 0; v < KK; ++v) {
            int xx = min(max(j + v - FF, 0), GG - 1);
            acc += o[yy * GG + xx] * w[u * KK + v];
        }
    }
    acc *= max_offset;
    acc = fminf(fmaxf(acc, -max_offset), max_offset);
    gs[idx] = acc;
}

// ---------------------------------------------------------------------------
// Kernel 2: block = 4-row x 256-col tile (R4 layout, keeps FETCH at ~77MB).
// Per pixel the two horizontal corners are fetched as ONE float2 (they're
// adjacent) -> 24 gathers/thread instead of 48. Edge cases: remap the two
// horizontal weights onto the float2 components via d = x0-clamp(x0,0,S-2).
// All 24 loads are forced to be in flight together (arrays + sched_barrier)
// to fix the G~2 loads-in-flight register-starvation seen in R3/R4.
// ---------------------------------------------------------------------------
__global__ __launch_bounds__(256, 4) void rds_deform_kernel(
    const float* __restrict__ x, const float* __restrict__ gs,
    float* __restrict__ out)
{
    int bx    = blockIdx.x;          // grid = BB * (SS/4) * 4
    int xseg  = bx & 3;
    int ytile = (bx >> 2) & 255;     // SS/4 = 256 tiles
    int b     = bx >> 10;
    int tid   = threadIdx.x;
    int ybase = ytile << 2;
    int xc    = (xseg << 8) + tid;

    __shared__ float rowf[4][2][GG];

    const float GdS = (float)GG / (float)SS;

    // Fill 4 rows x 2 channels x 10 cols of y-interpolated field
    if (tid < 80) {
        int p  = tid / 20;
        int r  = tid - p * 20;
        int ch = r / GG;
        int j  = r - ch * GG;
        int y  = ybase + p;
        float sy  = fmaxf(((float)y + 0.5f) * GdS - 0.5f, 0.0f);
        int   i0y = min((int)sy, GG - 1);
        int   i1y = min(i0y + 1, GG - 1);
        float wyu = sy - (float)i0y;
        const float* gb = gs + (b * 2 + ch) * GG * GG;
        rowf[p][ch][j] = gb[i0y * GG + j] + wyu * (gb[i1y * GG + j] - gb[i0y * GG + j]);
    }
    __syncthreads();

    // ---- x-direction quantities: once per thread ----
    float sx  = fmaxf(((float)xc + 0.5f) * GdS - 0.5f, 0.0f);
    int   i0x = min((int)sx, GG - 1);
    int   i1x = min(i0x + 1, GG - 1);
    float wxu = sx - (float)i0x;
    float pxc = (float)xc * (2.0f / (float)(SS - 1)) - 1.0f;

    int   oa[4], ob[4];          // float2 base offsets, rows cy0 / cy1
    float wxa[4], wxb[4];        // horizontal weights for f2.x / f2.y
    float wya[4], wyb[4];        // vertical weights incl. row masks

    #pragma unroll
    for (int p = 0; p < 4; ++p) {
        float r0a = rowf[p][0][i0x], r0b = rowf[p][0][i1x];
        float r1a = rowf[p][1][i0x], r1b = rowf[p][1][i1x];
        float gxv = r0a + wxu * (r0b - r0a);
        float gyv = r1a + wxu * (r1b - r1a);

        float py  = (float)(ybase + p) * (2.0f / (float)(SS - 1)) - 1.0f;
        float gr0 = fminf(fmaxf(gxv + pxc, -1.0f), 1.0f);
        float gr1 = fminf(fmaxf(gyv + py,  -1.0f), 1.0f);

        // ((gr+1)*S-1)/2 == gr*512 + 511.5
        float ix = gr0 * 512.0f + 511.5f;
        float iy = gr1 * 512.0f + 511.5f;

        int   x0 = (int)floorf(ix);      // in [-1, SS-1] after clip
        int   y0 = (int)floorf(iy);
        int   y1 = y0 + 1;
        float wx = ix - (float)x0;
        float wy = iy - (float)y0;

        // horizontal: one float2 load at base=clamp(x0,0,SS-2); d in {-1,0,1}
        int base = min(max(x0, 0), SS - 2);
        int d    = x0 - base;
        // d==0 : (1-wx)*f.x + wx*f.y   (both corners in range)
        // d==-1: x0=-1 -> corner x1=0 is f.x  -> wx*f.x
        // d==+1: x0=SS-1 -> corner x0 is f.y  -> (1-wx)*f.y
        wxa[p] = (d == 0) ? (1.0f - wx) : ((d < 0) ? wx : 0.0f);
        wxb[p] = (d == 0) ? wx          : ((d < 0) ? 0.0f : (1.0f - wx));

        float my0 = ((unsigned)y0 < (unsigned)SS) ? 1.0f : 0.0f;
        float my1 = ((unsigned)y1 < (unsigned)SS) ? 1.0f : 0.0f;
        wya[p] = (1.0f - wy) * my0;
        wyb[p] = wy * my1;

        int cy0 = min(max(y0, 0), SS - 1);
        int cy1 = min(max(y1, 0), SS - 1);
        oa[p] = cy0 * SS + base;
        ob[p] = cy1 * SS + base;
    }

    const float* xb = x + (size_t)b * CC * SS * SS;

    // ---- issue ALL 24 gathers; barrier pins them before any use ----
    f32x2 la[CC * 4], lb[CC * 4];
    #pragma unroll
    for (int c = 0; c < CC; ++c) {
        const float* img = xb + (size_t)c * SS * SS;
        #pragma unroll
        for (int p = 0; p < 4; ++p) {
            la[c * 4 + p] = *(const f32x2*)(img + oa[p]);
            lb[c * 4 + p] = *(const f32x2*)(img + ob[p]);
        }
    }
    __builtin_amdgcn_sched_barrier(0);

    // ---- FMAs + coalesced stores ----
    size_t obase = (((size_t)b * CC) * SS + ybase) * SS + xc;
    #pragma unroll
    for (int c = 0; c < CC; ++c) {
        #pragma unroll
        for (int p = 0; p < 4; ++p) {
            f32x2 fa = la[c * 4 + p];
            f32x2 fb = lb[c * 4 + p];
            float v = wya[p] * (fa.x * wxa[p] + fa.y * wxb[p])
                    + wyb[p] * (fb.x * wxa[p] + fb.y * wxb[p]);
            __builtin_nontemporal_store(
                v, out + obase + (size_t)c * SS * SS + (size_t)(p * SS));
        }
    }
}

extern "C" void kernel_launch(void* const* d_in, const int* in_sizes, int n_in,
                              void* d_out, int out_size, void* d_ws, size_t ws_size,
                              hipStream_t stream) {
    const float* x        = (const float*)d_in[0];
    const float* offset_x = (const float*)d_in[1];
    const float* offset_y = (const float*)d_in[2];
    const float* weight   = (const float*)d_in[3];
    const void*  max_move = d_in[4];
    float* out = (float*)d_out;
    float* gs  = (float*)d_ws;   // [B][2][G][G] smoothed, scaled, clipped field

    int n1 = BB * 2 * GG * GG;   // 1600
    rds_smooth_kernel<<<(n1 + 255) / 256, 256, 0, stream>>>(
        offset_x, offset_y, weight, max_move, gs);

    int nblocks = BB * (SS / 4) * 4;   // 8192: (b, ytile, xseg)
    rds_deform_kernel<<<nblocks, 256, 0, stream>>>(x, gs, out);
}